// Round 4
// baseline (408.537 us; speedup 1.0000x reference)
//
#include <hip/hip_runtime.h>
#include <hip/hip_bf16.h>
#include <math.h>

// ================= complex float helpers (prep, in-kernel) =================
struct cf { float x, y; };
__device__ __forceinline__ cf cfmul(cf a, cf b){ return {a.x*b.x - a.y*b.y, a.x*b.y + a.y*b.x}; }
__device__ __forceinline__ cf cfconj(cf a){ return {a.x, -a.y}; }
__device__ __forceinline__ cf cfadd(cf a, cf b){ return {a.x+b.x, a.y+b.y}; }

// S[d'*4+d] = sum_K K[i',a] * conj(K[j',b]),  d'=2i'+j', d=2a+b  (ket = high bit)
__device__ void superop_f(cf S[16], const cf* Ks, int nk){
    for (int i=0;i<16;i++) S[i] = {0.f,0.f};
    for (int n=0;n<nk;n++){
        const cf* K = Ks + n*4;
        for (int ip=0; ip<2; ip++) for (int jp=0; jp<2; jp++)
        for (int a=0; a<2; a++)   for (int b=0; b<2; b++){
            cf t = cfmul(K[ip*2+a], cfconj(K[jp*2+b]));
            int idx = (ip*2+jp)*4 + (a*2+b);
            S[idx] = cfadd(S[idx], t);
        }
    }
}

__device__ void mm4f(cf C[16], const cf A[16], const cf B[16]){
    for (int i=0;i<4;i++) for (int j=0;j<4;j++){
        cf s = {0.f,0.f};
        for (int k=0;k<4;k++) s = cfadd(s, cfmul(A[i*4+k], B[k*4+j]));
        C[i*4+j] = s;
    }
}

__device__ void build_dep_f(cf* dep, float p){
    float a = sqrtf(1.f-p), b = sqrtf(p/3.f);
    dep[0]={a,0.f};  dep[1]={0.f,0.f};  dep[2]={0.f,0.f}; dep[3]={a,0.f};    // I
    dep[4]={0.f,0.f};dep[5]={b,0.f};    dep[6]={b,0.f};   dep[7]={0.f,0.f};  // X
    dep[8]={0.f,0.f};dep[9]={0.f,-b};   dep[10]={0.f,b};  dep[11]={0.f,0.f}; // Y
    dep[12]={b,0.f}; dep[13]={0.f,0.f}; dep[14]={0.f,0.f};dep[15]={-b,0.f};  // Z
}

// ================= static phase configuration =================
// rho layout: digit j (= 9 - gate_qubit q) at bits (2j [bra], 2j+1 [ket]).
// K1: tile = global bits {0,1} + {10..19} (digits d5..d9), blockOffset bits 2..9.
// K2: tile = global bits {0..11}, blockOffset bits 12..19.
// K3: tile = global bits {0..9} + {18,19}, blockOffset bits 10..17.
// preA/preB: float2 offsets into sm (rot(l,q) = (l*10+q)*16, N2 = 480), -1 = none.
struct PCfg {
    unsigned um0, um1; int us0, us1, bs0, nops, doInit;
    int pa[4], pb[4], preA[4], preB[4];
};

__device__ const PCfg g_cfg[9] = {
  // layer 0
  {0x3u,  0xFFCu,0,8, 2, 4,1, {10,8,6,4},{8,6,4,2}, {0,-1,-1,-1},   {16,32,48,64}},
  {0xFFFu,0u,    0,0,12, 4,0, {10,8,6,4},{8,6,4,2}, {-1,-1,-1,-1},  {80,96,112,128}},
  {0x3FFu,0xC00u,0,8,10, 2,0, {2,0,0,0}, {0,10,2,2},{-1,-1,-1,-1},  {144,-1,-1,-1}},
  // layer 1
  {0x3u,  0xFFCu,0,8, 2, 4,0, {10,8,6,4},{8,6,4,2}, {160,-1,-1,-1}, {176,192,208,224}},
  {0xFFFu,0u,    0,0,12, 4,0, {10,8,6,4},{8,6,4,2}, {-1,-1,-1,-1},  {240,256,272,288}},
  {0x3FFu,0xC00u,0,8,10, 2,0, {2,0,0,0}, {0,10,2,2},{-1,-1,-1,-1},  {304,-1,-1,-1}},
  // layer 2
  {0x3u,  0xFFCu,0,8, 2, 4,0, {10,8,6,4},{8,6,4,2}, {320,-1,-1,-1}, {336,352,368,384}},
  {0xFFFu,0u,    0,0,12, 4,0, {10,8,6,4},{8,6,4,2}, {-1,-1,-1,-1},  {400,416,432,448}},
  {0x3FFu,0xC00u,0,8,10, 2,0, {2,0,0,0}, {0,10,2,2},{-1,-1,-1,-1},  {464,-1,-1,-1}},
};

#define CMUL_ACC(re,im,m,a) { re += (m).x*(a).x - (m).y*(a).y; im += (m).x*(a).y + (m).y*(a).x; }

#define ALONG_A(Mp) { _Pragma("unroll") for (int db_=0; db_<4; db_++){ \
    float2 a0=v[db_], a1=v[4+db_], a2=v[8+db_], a3=v[12+db_]; \
    _Pragma("unroll") for (int dp_=0; dp_<4; dp_++){ \
        float re=0.f, im=0.f; \
        CMUL_ACC(re,im,(Mp)[dp_*4+0],a0); CMUL_ACC(re,im,(Mp)[dp_*4+1],a1); \
        CMUL_ACC(re,im,(Mp)[dp_*4+2],a2); CMUL_ACC(re,im,(Mp)[dp_*4+3],a3); \
        v[dp_*4+db_] = make_float2(re,im); } } }

#define ALONG_B(Mp) { _Pragma("unroll") for (int da_=0; da_<4; da_++){ \
    float2 a0=v[da_*4+0], a1=v[da_*4+1], a2=v[da_*4+2], a3=v[da_*4+3]; \
    _Pragma("unroll") for (int dp_=0; dp_<4; dp_++){ \
        float re=0.f, im=0.f; \
        CMUL_ACC(re,im,(Mp)[dp_*4+0],a0); CMUL_ACC(re,im,(Mp)[dp_*4+1],a1); \
        CMUL_ACC(re,im,(Mp)[dp_*4+2],a2); CMUL_ACC(re,im,(Mp)[dp_*4+3],a3); \
        v[da_*4+dp_] = make_float2(re,im); } } }

// ============ software grid barrier (monotonic counter, 256 blocks) ============
// Counter zeroed by hipMemsetAsync before every launch. Release = threadfence
// (L2 writeback at agent scope), acquire = threadfence after spin (invalidate).
// Deadlock-free: grid (256 blocks) <= device capacity, so all blocks become
// resident while others spin.
__device__ __forceinline__ void grid_barrier(unsigned* cnt, int tid){
    __syncthreads();
    if (tid == 0){
        __threadfence();
        unsigned old = __hip_atomic_fetch_add(cnt, 1u, __ATOMIC_RELAXED, __HIP_MEMORY_SCOPE_AGENT);
        unsigned need = (old & ~255u) + 256u;
        while (__hip_atomic_load(cnt, __ATOMIC_RELAXED, __HIP_MEMORY_SCOPE_AGENT) < need)
            __builtin_amdgcn_s_sleep(2);
        __threadfence();
    }
    __syncthreads();
}

// ================= the single monolithic kernel =================
__global__ void __launch_bounds__(256, 1)
nisq_mono(float2* __restrict__ rho, float* __restrict__ cvec, unsigned* __restrict__ bar,
          const float* __restrict__ wts, const float* __restrict__ x,
          const float* __restrict__ bvec, const float* __restrict__ w,
          float* __restrict__ out)
{
    __shared__ __align__(16) float2 tile[4096];
    __shared__ float2 sm[31*16];
    __shared__ float red[4];
    __shared__ float cX[10], cZ[10];
    int tid = threadIdx.x;
    int blk = blockIdx.x;

    // ---- prep (threads 0..30 of EVERY block, fp32, redundant) ----
    if (tid < 31){
        const float GA = -expm1f(-2.0000000000000002e-06f);   // 1-exp(-GATE/T1)
        const float GP = -expm1f(-1.4285714285714286e-06f);   // 1-exp(-GATE/T2)
        cf amp[8], ph[8], kr[16];
        { float s1=sqrtf(1.f-GA), s2=sqrtf(GA);
          amp[0]={1.f,0.f}; amp[1]={0.f,0.f}; amp[2]={0.f,0.f}; amp[3]={s1,0.f};
          amp[4]={0.f,0.f}; amp[5]={s2,0.f};  amp[6]={0.f,0.f}; amp[7]={0.f,0.f}; }
        { float s1=sqrtf(1.f-GP), s2=sqrtf(GP);
          ph[0]={1.f,0.f}; ph[1]={0.f,0.f}; ph[2]={0.f,0.f}; ph[3]={s1,0.f};
          ph[4]={0.f,0.f}; ph[5]={0.f,0.f}; ph[6]={0.f,0.f}; ph[7]={s2,0.f}; }
        cf Sdep[16], Samp[16], Sph[16], NN[16], tmp[16];
        superop_f(Samp, amp, 2);
        superop_f(Sph, ph, 2);
        if (tid == 30){
            build_dep_f(kr, 0.01f); superop_f(Sdep, kr, 4);
            mm4f(tmp, Samp, Sdep); mm4f(NN, Sph, tmp);        // N2
            for (int i=0;i<16;i++) sm[480+i] = make_float2(NN[i].x, NN[i].y);
        } else {
            build_dep_f(kr, 0.001f); superop_f(Sdep, kr, 4);
            mm4f(tmp, Samp, Sdep); mm4f(NN, Sph, tmp);        // N1
            float phi = wts[tid*3+0], th = wts[tid*3+1], om = wts[tid*3+2];
            float ct = cosf(0.5f*th), st = sinf(0.5f*th);
            cf ep = {cosf(0.5f*(phi+om)), -sinf(0.5f*(phi+om))};
            cf em = {cosf(0.5f*(phi-om)),  sinf(0.5f*(phi-om))};
            cf R[4];
            R[0] = { ep.x*ct,  ep.y*ct};
            R[1] = {-em.x*st, -em.y*st};
            R[2] = { em.x*st, -em.y*st};
            R[3] = { ep.x*ct, -ep.y*ct};
            cf Sr[16];
            for (int i2=0;i2<2;i2++) for (int j2=0;j2<2;j2++)
            for (int a=0;a<2;a++)    for (int b2=0;b2<2;b2++)
                Sr[(i2*2+j2)*4+(a*2+b2)] = cfmul(R[i2*2+a], cfconj(R[j2*2+b2]));
            cf S[16]; mm4f(S, NN, Sr);
            for (int i=0;i<16;i++) sm[tid*16+i] = make_float2(S[i].x, S[i].y);
        }
    }
    __syncthreads();

    // ---- 9 sim phases with software grid barrier between repartitions ----
    for (int p=0; p<9; p++){
        const PCfg& c = g_cfg[p];
        unsigned bo = ((unsigned)blk) << c.bs0;
        if (c.doInit){
#pragma unroll
            for (int r=0; r<16; r++){
                unsigned u = tid + 256u*r;
                float val = (blk==0 && u==0) ? 1.f : 0.f;
                tile[u ^ ((u>>6)&62u)] = make_float2(val, 0.f);
            }
        } else {
#pragma unroll
            for (int r=0; r<8; r++){
                unsigned u = 2u*(tid + 256u*r);
                unsigned g = bo + ((u & c.um0) << c.us0) + ((u & c.um1) << c.us1);
                unsigned s = u ^ ((u>>6)&62u);
                *reinterpret_cast<float4*>(&tile[s]) = *reinterpret_cast<const float4*>(rho + g);
            }
        }
        __syncthreads();

#pragma unroll
        for (int op=0; op<4; op++){
            if (op < c.nops){
                int pa = c.pa[op], pb = c.pb[op];
                int lo = pa < pb ? pa : pb, hi = pa < pb ? pb : pa;
                unsigned g8 = (unsigned)tid;
                unsigned xx = ((g8 >> lo) << (lo+2)) | (g8 & ((1u<<lo)-1u));
                xx = ((xx >> hi) << (hi+2)) | (xx & ((1u<<hi)-1u));
                unsigned adr[16];
                float2 v[16];
#pragma unroll
                for (int d=0; d<16; d++){
                    unsigned t = xx | ((unsigned)(d>>2) << pa) | ((unsigned)(d&3) << pb);
                    adr[d] = t ^ ((t>>6)&62u);
                    v[d] = tile[adr[d]];
                }
                int mA = c.preA[op], mB = c.preB[op];
                if (mA >= 0) { const float2* M = sm + mA; ALONG_A(M); }
                if (mB >= 0) { const float2* M = sm + mB; ALONG_B(M); }
                { // CNOT perm: v[da][db] <- v[da][db^da]
                    float2 t0;
                    t0=v[4];  v[4]=v[5];   v[5]=t0;
                    t0=v[6];  v[6]=v[7];   v[7]=t0;
                    t0=v[8];  v[8]=v[10];  v[10]=t0;
                    t0=v[9];  v[9]=v[11];  v[11]=t0;
                    t0=v[12]; v[12]=v[15]; v[15]=t0;
                    t0=v[13]; v[13]=v[14]; v[14]=t0;
                }
                { const float2* M = sm + 480; ALONG_B(M); ALONG_A(M); }  // N2 target, N2 control
#pragma unroll
                for (int d=0; d<16; d++) tile[adr[d]] = v[d];
            }
            __syncthreads();
        }

#pragma unroll
        for (int r=0; r<8; r++){
            unsigned u = 2u*(tid + 256u*r);
            unsigned g = bo + ((u & c.um0) << c.us0) + ((u & c.um1) << c.us1);
            unsigned s = u ^ ((u>>6)&62u);
            *reinterpret_cast<float4*>(rho + g) = *reinterpret_cast<const float4*>(&tile[s]);
        }
        grid_barrier(bar, tid);
    }

    // ---- trace: blocks 0..19 compute cvec[k] = w[k]*scale*Re tr(P_k rho) ----
    if (blk < 20){
        int k = blk, q = k >> 1, j = 9 - q;
        float acc = 0.f;
#pragma unroll
        for (int r=0; r<4; r++){
            unsigned m = tid + 256u*r;
            unsigned xg = m;
            xg = (xg | (xg<<8)) & 0x00FF00FFu;
            xg = (xg | (xg<<4)) & 0x0F0F0F0Fu;
            xg = (xg | (xg<<2)) & 0x33333333u;
            xg = (xg | (xg<<1)) & 0x55555555u;
            unsigned diag = 3u*xg;      // ket=bra=m, digit-interleaved
            if (k & 1){
                float d = rho[diag].x;
                acc += ((m >> j) & 1u) ? -d : d;
            } else {
                acc += rho[diag ^ (1u << (2*j+1))].x;
            }
        }
        for (int o=32; o>0; o>>=1) acc += __shfl_down(acc, o);
        if ((tid & 63) == 0) red[tid>>6] = acc;
        __syncthreads();
        if (tid == 0){
            float scale = (k & 1) ? 0.96f : 1.0f;   // readout bitflip folded: Z *= 1-2*0.02
            cvec[k] = w[k] * scale * (red[0]+red[1]+red[2]+red[3]);
        }
    }
    grid_barrier(bar, tid);

    // ---- logits: each block handles 8 batches ----
    if (tid < 10){ cX[tid] = cvec[2*tid]; cZ[tid] = cvec[2*tid+1]; }
    float* xs = reinterpret_cast<float*>(tile);
    for (int bi=0; bi<8; bi++){
        int b = blk + 256*bi;
#pragma unroll
        for (int r=0; r<4; r++){
            int m = tid + r*256;
            xs[m] = x[b*1024 + m] + bvec[m];
        }
        __syncthreads();
        float acc = 0.f;
#pragma unroll
        for (int r=0; r<4; r++){
            int m = tid + r*256;
            float xm = xs[m];
            float sd = 0.f;
#pragma unroll
            for (int qq=0; qq<10; qq++){
                float cz = cZ[qq];
                sd += (m & (1<<(9-qq))) ? -cz : cz;
                acc += cX[qq] * xm * xs[m ^ (1<<(9-qq))];
            }
            acc += sd * xm * xm;
        }
        for (int o=32; o>0; o>>=1) acc += __shfl_down(acc, o);
        if ((tid & 63) == 0) red[tid>>6] = acc;
        __syncthreads();
        if (tid == 0){
            float l = red[0]+red[1]+red[2]+red[3];
            out[b] = 1.f / (1.f + expf(-l));
        }
        __syncthreads();
    }
}

// ================= launch =================
extern "C" void kernel_launch(void* const* d_in, const int* in_sizes, int n_in,
                              void* d_out, int out_size, void* d_ws, size_t ws_size,
                              hipStream_t stream) {
    const float* x    = (const float*)d_in[0];   // [2048,1024]
    const float* bvec = (const float*)d_in[1];   // [1024]
    const float* w    = (const float*)d_in[2];   // [20]
    const float* cw   = (const float*)d_in[3];   // [3,10,3]
    float* out = (float*)d_out;

    char* ws = (char*)d_ws;
    float2*   rho  = (float2*)ws;                                   // 2^20 float2 = 8 MB
    float*    cvec = (float*)(ws + (size_t)(1u<<20)*sizeof(float2));
    unsigned* bar  = (unsigned*)(ws + (size_t)(1u<<20)*sizeof(float2) + 128);
    (void)ws_size; (void)in_sizes; (void)n_in; (void)out_size;

    hipMemsetAsync(bar, 0, sizeof(unsigned), stream);
    nisq_mono<<<256, 256, 0, stream>>>(rho, cvec, bar, cw, x, bvec, w, out);
}

// Round 5
// 133.510 us; speedup vs baseline: 3.0600x; 3.0600x over previous
//
#include <hip/hip_runtime.h>
#include <hip/hip_bf16.h>
#include <math.h>

// ================= complex float helpers (prep, in-kernel) =================
struct cf { float x, y; };
__device__ __forceinline__ cf cfmul(cf a, cf b){ return {a.x*b.x - a.y*b.y, a.x*b.y + a.y*b.x}; }
__device__ __forceinline__ cf cfconj(cf a){ return {a.x, -a.y}; }
__device__ __forceinline__ cf cfadd(cf a, cf b){ return {a.x+b.x, a.y+b.y}; }

// S[d'*4+d] = sum_K K[i',a] * conj(K[j',b]),  d'=2i'+j', d=2a+b  (ket = high bit)
__device__ void superop_f(cf S[16], const cf* Ks, int nk){
    for (int i=0;i<16;i++) S[i] = {0.f,0.f};
    for (int n=0;n<nk;n++){
        const cf* K = Ks + n*4;
        for (int ip=0; ip<2; ip++) for (int jp=0; jp<2; jp++)
        for (int a=0; a<2; a++)   for (int b=0; b<2; b++){
            cf t = cfmul(K[ip*2+a], cfconj(K[jp*2+b]));
            int idx = (ip*2+jp)*4 + (a*2+b);
            S[idx] = cfadd(S[idx], t);
        }
    }
}

__device__ void mm4f(cf C[16], const cf A[16], const cf B[16]){
    for (int i=0;i<4;i++) for (int j=0;j<4;j++){
        cf s = {0.f,0.f};
        for (int k=0;k<4;k++) s = cfadd(s, cfmul(A[i*4+k], B[k*4+j]));
        C[i*4+j] = s;
    }
}

__device__ void build_dep_f(cf* dep, float p){
    float a = sqrtf(1.f-p), b = sqrtf(p/3.f);
    dep[0]={a,0.f};  dep[1]={0.f,0.f};  dep[2]={0.f,0.f}; dep[3]={a,0.f};    // I
    dep[4]={0.f,0.f};dep[5]={b,0.f};    dep[6]={b,0.f};   dep[7]={0.f,0.f};  // X
    dep[8]={0.f,0.f};dep[9]={0.f,-b};   dep[10]={0.f,b};  dep[11]={0.f,0.f}; // Y
    dep[12]={b,0.f}; dep[13]={0.f,0.f}; dep[14]={0.f,0.f};dep[15]={-b,0.f};  // Z
}

// in-kernel prep: threads 0..30 fill sm[0..495]
// sm[(l*10+q)*16 .. +15] = N1 * Rot(l,q); sm[480..495] = N2
__device__ void prep_sm(float2* sm, const float* __restrict__ wts, int tid){
    if (tid < 31){
        const float GA = -expm1f(-2.0000000000000002e-06f);   // 1-exp(-GATE/T1)
        const float GP = -expm1f(-1.4285714285714286e-06f);   // 1-exp(-GATE/T2)
        cf amp[8], ph[8], kr[16];
        { float s1=sqrtf(1.f-GA), s2=sqrtf(GA);
          amp[0]={1.f,0.f}; amp[1]={0.f,0.f}; amp[2]={0.f,0.f}; amp[3]={s1,0.f};
          amp[4]={0.f,0.f}; amp[5]={s2,0.f};  amp[6]={0.f,0.f}; amp[7]={0.f,0.f}; }
        { float s1=sqrtf(1.f-GP), s2=sqrtf(GP);
          ph[0]={1.f,0.f}; ph[1]={0.f,0.f}; ph[2]={0.f,0.f}; ph[3]={s1,0.f};
          ph[4]={0.f,0.f}; ph[5]={0.f,0.f}; ph[6]={0.f,0.f}; ph[7]={s2,0.f}; }
        cf Sdep[16], Samp[16], Sph[16], NN[16], tmp[16];
        superop_f(Samp, amp, 2);
        superop_f(Sph, ph, 2);
        if (tid == 30){
            build_dep_f(kr, 0.01f); superop_f(Sdep, kr, 4);
            mm4f(tmp, Samp, Sdep); mm4f(NN, Sph, tmp);        // N2
            for (int i=0;i<16;i++) sm[480+i] = make_float2(NN[i].x, NN[i].y);
        } else {
            build_dep_f(kr, 0.001f); superop_f(Sdep, kr, 4);
            mm4f(tmp, Samp, Sdep); mm4f(NN, Sph, tmp);        // N1
            float phi = wts[tid*3+0], th = wts[tid*3+1], om = wts[tid*3+2];
            float ct = cosf(0.5f*th), st = sinf(0.5f*th);
            cf ep = {cosf(0.5f*(phi+om)), -sinf(0.5f*(phi+om))};
            cf em = {cosf(0.5f*(phi-om)),  sinf(0.5f*(phi-om))};
            cf R[4];
            R[0] = { ep.x*ct,  ep.y*ct};
            R[1] = {-em.x*st, -em.y*st};
            R[2] = { em.x*st, -em.y*st};
            R[3] = { ep.x*ct, -ep.y*ct};
            cf Sr[16];
            for (int i2=0;i2<2;i2++) for (int j2=0;j2<2;j2++)
            for (int a=0;a<2;a++)    for (int b2=0;b2<2;b2++)
                Sr[(i2*2+j2)*4+(a*2+b2)] = cfmul(R[i2*2+a], cfconj(R[j2*2+b2]));
            cf S[16]; mm4f(S, NN, Sr);
            for (int i=0;i<16;i++) sm[tid*16+i] = make_float2(S[i].x, S[i].y);
        }
    }
}

#define CMUL_ACC(re,im,m,a) { re += (m).x*(a).x - (m).y*(a).y; im += (m).x*(a).y + (m).y*(a).x; }

#define ALONG_A(Mp) { _Pragma("unroll") for (int db_=0; db_<4; db_++){ \
    float2 a0=v[db_], a1=v[4+db_], a2=v[8+db_], a3=v[12+db_]; \
    _Pragma("unroll") for (int dp_=0; dp_<4; dp_++){ \
        float re=0.f, im=0.f; \
        CMUL_ACC(re,im,(Mp)[dp_*4+0],a0); CMUL_ACC(re,im,(Mp)[dp_*4+1],a1); \
        CMUL_ACC(re,im,(Mp)[dp_*4+2],a2); CMUL_ACC(re,im,(Mp)[dp_*4+3],a3); \
        v[dp_*4+db_] = make_float2(re,im); } } }

#define ALONG_B(Mp) { _Pragma("unroll") for (int da_=0; da_<4; da_++){ \
    float2 a0=v[da_*4+0], a1=v[da_*4+1], a2=v[da_*4+2], a3=v[da_*4+3]; \
    _Pragma("unroll") for (int dp_=0; dp_<4; dp_++){ \
        float re=0.f, im=0.f; \
        CMUL_ACC(re,im,(Mp)[dp_*4+0],a0); CMUL_ACC(re,im,(Mp)[dp_*4+1],a1); \
        CMUL_ACC(re,im,(Mp)[dp_*4+2],a2); CMUL_ACC(re,im,(Mp)[dp_*4+3],a3); \
        v[da_*4+dp_] = make_float2(re,im); } } }

// ================= fused phase kernel =================
// rho layout (float2 index, 20 bits): digit d at position p(d):
//   p: d9->0, d4->1, d5->2, d6->3, d7->4, d8->5, d0->6, d1->7, d2->8, d3->9.
//   digit at position p occupies bits (2p = bra, 2p+1 = ket).
// Phase A (isB=0): tile = bits 0..11 (digits d9,d4,d5..d8); block -> bits 12..19.
//   ops: CNOT(0,1)..(4,5) = (d9,d8),(d8,d7),(d7,d6),(d6,d5),(d5,d4)
// Phase B (isB=1): tile = bits 0..3 + 12..19 (digits d9,d4,d0..d3); block -> bits 4..11.
//   ops: CNOT(5,6)..(9,0) = (d4,d3),(d3,d2),(d2,d1),(d1,d0),(d0,d9)
__global__ void __launch_bounds__(256)
fused6(float2* __restrict__ rho, const float* __restrict__ wts,
       int layer, int isB, int doInit)
{
    __shared__ __align__(16) float2 tile[4096];
    __shared__ float2 sm[31*16];
    int tid = threadIdx.x;
    unsigned blk = blockIdx.x;

    prep_sm(sm, wts, tid);

    unsigned bo = blk << (isB ? 4 : 12);
    if (doInit){
#pragma unroll
        for (int r=0; r<16; r++){
            unsigned u = tid + 256u*r;
            float val = (blk==0 && u==0) ? 1.f : 0.f;
            tile[u ^ ((u>>6)&62u)] = make_float2(val, 0.f);
        }
    } else {
#pragma unroll
        for (int r=0; r<8; r++){
            unsigned u = 2u*(tid + 256u*r);
            unsigned g = isB ? ((u & 14u) | ((u >> 4) << 12) | bo) : (u | bo);
            unsigned s = u ^ ((u>>6)&62u);
            *reinterpret_cast<float4*>(&tile[s]) = *reinterpret_cast<const float4*>(rho + g);
        }
    }
    __syncthreads();

    // op tables (tile bit positions of control/target digit pairs)
    const int A_PA[5] = {0,10,8,6,4}, A_PB[5] = {10,8,6,4,2};
    const int B_PA[5] = {2,10,8,6,4}, B_PB[5] = {10,8,6,4,0};

#pragma unroll
    for (int i=0; i<5; i++){
        int pa = isB ? B_PA[i] : A_PA[i];
        int pb = isB ? B_PB[i] : A_PB[i];
        int mA = (!isB && i==0) ? layer*160 : -1;                 // rot(l,0) on d9 control
        int mB;
        if (!isB) mB = (layer*10 + i + 1)*16;                      // rot(l,1..5)
        else      mB = (i < 4) ? (layer*10 + 6 + i)*16 : -1;       // rot(l,6..9), none on last
        int lo = pa < pb ? pa : pb, hi = pa < pb ? pb : pa;
        unsigned g8 = (unsigned)tid;
        unsigned xx = ((g8 >> lo) << (lo+2)) | (g8 & ((1u<<lo)-1u));
        xx = ((xx >> hi) << (hi+2)) | (xx & ((1u<<hi)-1u));
        unsigned adr[16];
        float2 v[16];
#pragma unroll
        for (int d=0; d<16; d++){
            unsigned t = xx | ((unsigned)(d>>2) << pa) | ((unsigned)(d&3) << pb);
            adr[d] = t ^ ((t>>6)&62u);
            v[d] = tile[adr[d]];
        }
        if (mA >= 0) { const float2* M = sm + mA; ALONG_A(M); }
        if (mB >= 0) { const float2* M = sm + mB; ALONG_B(M); }
        { // CNOT perm: v[da][db] <- v[da][db^da]
            float2 t0;
            t0=v[4];  v[4]=v[5];   v[5]=t0;
            t0=v[6];  v[6]=v[7];   v[7]=t0;
            t0=v[8];  v[8]=v[10];  v[10]=t0;
            t0=v[9];  v[9]=v[11];  v[11]=t0;
            t0=v[12]; v[12]=v[15]; v[15]=t0;
            t0=v[13]; v[13]=v[14]; v[14]=t0;
        }
        { const float2* M = sm + 480; ALONG_B(M); ALONG_A(M); }   // N2 target, N2 control
#pragma unroll
        for (int d=0; d<16; d++) tile[adr[d]] = v[d];
        __syncthreads();
    }

#pragma unroll
    for (int r=0; r<8; r++){
        unsigned u = 2u*(tid + 256u*r);
        unsigned g = isB ? ((u & 14u) | ((u >> 4) << 12) | bo) : (u | bo);
        unsigned s = u ^ ((u>>6)&62u);
        *reinterpret_cast<float4*>(rho + g) = *reinterpret_cast<const float4*>(&tile[s]);
    }
}

// ================= trace: cvec[k] = w[k]*scale*Re tr(P_k rho) =================
__global__ void __launch_bounds__(256)
trace_kernel(const float2* __restrict__ rho, const float* __restrict__ w,
             float* __restrict__ cvec)
{
    // qubit q -> digit d(9-q) -> position table
    const int PQ[10] = {0,5,4,3,2,1,9,8,7,6};
    int k = blockIdx.x, q = k >> 1;
    int p = PQ[q];
    int tid = threadIdx.x;
    float acc = 0.f;
#pragma unroll
    for (int r=0; r<4; r++){
        unsigned m = tid + 256u*r;           // bit p of m = digit value at position p
        unsigned xg = m;
        xg = (xg | (xg<<8)) & 0x00FF00FFu;
        xg = (xg | (xg<<4)) & 0x0F0F0F0Fu;
        xg = (xg | (xg<<2)) & 0x33333333u;
        xg = (xg | (xg<<1)) & 0x55555555u;
        unsigned diag = 3u*xg;               // ket=bra
        if (k & 1){
            float d = rho[diag].x;
            acc += ((m >> p) & 1u) ? -d : d;
        } else {
            acc += rho[diag ^ (1u << (2*p+1))].x;
        }
    }
    for (int o=32; o>0; o>>=1) acc += __shfl_down(acc, o);
    __shared__ float red[4];
    if ((tid & 63) == 0) red[tid>>6] = acc;
    __syncthreads();
    if (tid == 0){
        float scale = (k & 1) ? 0.96f : 1.0f;   // readout bitflip folded: Z *= 1-2*0.02
        cvec[k] = w[k] * scale * (red[0]+red[1]+red[2]+red[3]);
    }
}

// ================= head: logits + sigmoid =================
__global__ void __launch_bounds__(256)
logits_kernel(const float* __restrict__ x, const float* __restrict__ bvec,
              const float* __restrict__ cvec, float* __restrict__ out)
{
    __shared__ float xs[1024];
    __shared__ float cX[10], cZ[10];
    __shared__ float red[4];
    int b = blockIdx.x, tid = threadIdx.x;
    if (tid < 10){ cX[tid] = cvec[2*tid]; cZ[tid] = cvec[2*tid+1]; }
    {
        float4 xv = reinterpret_cast<const float4*>(x + (size_t)b*1024)[tid];
        float4 bv = reinterpret_cast<const float4*>(bvec)[tid];
        xs[tid*4+0] = xv.x + bv.x;
        xs[tid*4+1] = xv.y + bv.y;
        xs[tid*4+2] = xv.z + bv.z;
        xs[tid*4+3] = xv.w + bv.w;
    }
    __syncthreads();
    float acc = 0.f;
#pragma unroll
    for (int r=0; r<4; r++){
        int m = tid + r*256;
        float xm = xs[m];
        float sd = 0.f;
#pragma unroll
        for (int qq=0; qq<10; qq++){
            float cz = cZ[qq];
            sd += (m & (1<<(9-qq))) ? -cz : cz;
            acc += cX[qq] * xm * xs[m ^ (1<<(9-qq))];
        }
        acc += sd * xm * xm;
    }
    for (int o=32; o>0; o>>=1) acc += __shfl_down(acc, o);
    if ((tid & 63) == 0) red[tid>>6] = acc;
    __syncthreads();
    if (tid == 0){
        float l = red[0]+red[1]+red[2]+red[3];
        out[b] = 1.f / (1.f + expf(-l));
    }
}

// ================= launch =================
extern "C" void kernel_launch(void* const* d_in, const int* in_sizes, int n_in,
                              void* d_out, int out_size, void* d_ws, size_t ws_size,
                              hipStream_t stream) {
    const float* x    = (const float*)d_in[0];   // [2048,1024]
    const float* bvec = (const float*)d_in[1];   // [1024]
    const float* w    = (const float*)d_in[2];   // [20]
    const float* cw   = (const float*)d_in[3];   // [3,10,3]
    float* out = (float*)d_out;

    char* ws = (char*)d_ws;
    float2* rho  = (float2*)ws;                                   // 2^20 float2 = 8 MB
    float*  cvec = (float*)(ws + (size_t)(1u<<20)*sizeof(float2));
    (void)ws_size; (void)in_sizes; (void)n_in; (void)out_size;

    for (int l=0; l<3; l++){
        fused6<<<256, 256, 0, stream>>>(rho, cw, l, 0, (l==0) ? 1 : 0);
        fused6<<<256, 256, 0, stream>>>(rho, cw, l, 1, 0);
    }
    trace_kernel<<<20, 256, 0, stream>>>(rho, w, cvec);
    logits_kernel<<<2048, 256, 0, stream>>>(x, bvec, cvec, out);
}